// Round 2
// baseline (200.037 us; speedup 1.0000x reference)
//
#include <hip/hip_runtime.h>

#define BATCH   2048
#define NPAR    256
#define NF      32
#define NG      16
#define NBR     4
#define OFS     262144
#define DOUT    128
#define NROWSX  (OFS + NPAR*BATCH)     // 786432 rows of x
#define MROWS   (NPAR*BATCH)           // 524288 parent rows
#define NTILES  (MROWS/16)             // 32768 16-row tiles
#define CHBASE  (NROWSX*NF)            // float offset of children region in out
#define MLPBLK  2048                   // blocks doing MLP work
#define CPBLK   2048                   // blocks doing the x->out copy

typedef short bf16x8 __attribute__((ext_vector_type(8)));   // 8 bf16 bit-patterns
typedef float f32x4  __attribute__((ext_vector_type(4)));

__device__ __forceinline__ unsigned short f2bf(float f){
  unsigned int u = __float_as_uint(f);
  u += 0x7FFFu + ((u >> 16) & 1u);          // RNE
  return (unsigned short)(u >> 16);
}

// G1[e][j] = b1[j] + sum_k global[e][k] * W1[32+k][j]
__global__ void k_g1(const float* __restrict__ gf, const float* __restrict__ W1,
                     const float* __restrict__ b1, float* __restrict__ G1){
  int idx = blockIdx.x*blockDim.x + threadIdx.x;
  if (idx >= BATCH*DOUT) return;
  int e = idx >> 7, j = idx & 127;
  float s = b1[j];
  const float* grow = gf + e*NG;
  const float* w = W1 + NF*DOUT + j;
  #pragma unroll
  for (int k = 0; k < NG; k++) s = fmaf(grow[k], w[k*DOUT], s);
  G1[idx] = s;
}

// Merged kernel: blocks [0,MLPBLK) run the MLP; blocks [MLPBLK, MLPBLK+CPBLK)
// run the x -> out[0:NROWSX] verbatim copy (grid-stride float4).
__global__ __launch_bounds__(256) void k_main(
    const float* __restrict__ x, const int* __restrict__ pidx,
    const float* __restrict__ W1, const float* __restrict__ W2,
    const float* __restrict__ b2, const float* __restrict__ G1,
    float* __restrict__ out)
{
  __shared__ uint4 ldsB2[2048];   // 32 KB: W2 B-fragments, [frag(kk*8+n)][lane] * 16B
  __shared__ uint4 ldsH1[1024];   // 16 KB: per-wave 4KB h1 tile (bf16, swizzled)

  const int bid = blockIdx.x;
  const int tid = threadIdx.x;

  if (bid >= MLPBLK){
    // ---- copy path: 200 MB, pure bandwidth ----
    const int n = NROWSX*NF/4;
    const float4* src4 = (const float4*)x;
    float4* dst4 = (float4*)out;
    for (int i = (bid - MLPBLK)*256 + tid; i < n; i += CPBLK*256)
      dst4[i] = src4[i];
    return;
  }

  const int lane = tid & 63;
  const int wv   = tid >> 6;
  const int r15  = lane & 15;
  const int g    = lane >> 4;

  // ---- stage W2 B-fragments into LDS (once per block) ----
  for (int p = tid; p < 32*64; p += 256){
    int f = p >> 6, l = p & 63;
    int kk = f >> 3, n = f & 7;
    int krow = 32*kk + 8*(l >> 4);
    int col  = 16*n + (l & 15);
    union { uint4 q; unsigned short u[8]; } w;
    #pragma unroll
    for (int e = 0; e < 8; e++) w.u[e] = f2bf(W2[(krow + e)*DOUT + col]);
    ldsB2[p] = w.q;
  }

  // ---- W1 (feature half) B-fragments in registers ----
  bf16x8 b1f[8];
  {
    int kb = 8*g;
    #pragma unroll
    for (int n = 0; n < 8; n++){
      union { bf16x8 v; unsigned short u[8]; } w;
      #pragma unroll
      for (int e = 0; e < 8; e++) w.u[e] = f2bf(W1[(kb + e)*DOUT + 16*n + r15]);
      b1f[n] = w.v;
    }
  }

  __syncthreads();

  char* h1base = (char*)ldsH1 + wv*4096;
  const bf16x8* B2f = (const bf16x8*)ldsB2;

  for (int j = 0; j < 4; j++){
    const int tl   = bid*16 + j*4 + wv;   // tile index
    const int row0 = tl*16;

    // This lane's batch row within the tile is r15 (transposed layout).
    const int idxA = pidx[row0 + r15];

    // x row: A1/B1 fragment (cols 8g..8g+7) + residual scalars (col 4n+g)
    const float* ap = x + idxA*NF + 8*g;
    float4 a0 = *(const float4*)ap;
    float4 a1 = *(const float4*)(ap + 4);
    float xres[8];
    #pragma unroll
    for (int n = 0; n < 8; n++) xres[n] = x[idxA*NF + 4*n + g];

    union { bf16x8 v; unsigned short u[8]; } af;
    af.u[0]=f2bf(a0.x); af.u[1]=f2bf(a0.y); af.u[2]=f2bf(a0.z); af.u[3]=f2bf(a0.w);
    af.u[4]=f2bf(a1.x); af.u[5]=f2bf(a1.y); af.u[6]=f2bf(a1.z); af.u[7]=f2bf(a1.w);

    // GEMM1 (transposed): acc1[n][r] = h1^T[16n+4g+r][r15],
    // preloaded with G1 (bias + global half folded in) -> float4 loads.
    const int g1r = idxA & (BATCH-1);
    f32x4 acc1[8];
    #pragma unroll
    for (int n = 0; n < 8; n++)
      acc1[n] = *(const f32x4*)(G1 + g1r*DOUT + 16*n + 4*g);
    #pragma unroll
    for (int n = 0; n < 8; n++)
      acc1[n] = __builtin_amdgcn_mfma_f32_16x16x32_bf16(b1f[n], af.v, acc1[n], 0, 0, 0);

    // leaky-relu, pack 4 bf16, ds_write_b64 into swizzled [16][128] tile
    #pragma unroll
    for (int n = 0; n < 8; n++){
      float v0 = acc1[n][0], v1 = acc1[n][1], v2 = acc1[n][2], v3 = acc1[n][3];
      v0 = v0 > 0.f ? v0 : 0.01f*v0;
      v1 = v1 > 0.f ? v1 : 0.01f*v1;
      v2 = v2 > 0.f ? v2 : 0.01f*v2;
      v3 = v3 > 0.f ? v3 : 0.01f*v3;
      uint2 pk;
      pk.x = (unsigned)f2bf(v0) | ((unsigned)f2bf(v1) << 16);
      pk.y = (unsigned)f2bf(v2) | ((unsigned)f2bf(v3) << 16);
      int off = r15*256 + (16*n + 4*g)*2;
      off ^= (r15 & 7) << 4;
      *(uint2*)(h1base + off) = pk;
    }
    // wave-private LDS: compiler orders via lgkmcnt; no barrier needed.

    // GEMM2 (transposed): acc2[n][r] = proj^T[16n+4g+r][r15], b2 folded into init
    f32x4 acc2[8];
    #pragma unroll
    for (int n = 0; n < 8; n++)
      acc2[n] = *(const f32x4*)(b2 + 16*n + 4*g);
    #pragma unroll
    for (int kk = 0; kk < 4; kk++){
      int roff = r15*256 + 64*kk + 16*g;
      roff ^= (r15 & 7) << 4;
      bf16x8 a2 = *(const bf16x8*)(h1base + roff);
      #pragma unroll
      for (int n = 0; n < 8; n++)
        acc2[n] = __builtin_amdgcn_mfma_f32_16x16x32_bf16(B2f[(kk*8 + n)*64 + lane], a2, acc2[n], 0, 0, 0);
    }

    // epilogue: + repeat_interleave residual (col>>2 = 4n+g, constant over r),
    // float4 store to children layout
    const int p  = row0 >> 11;           // parent (tiles never cross parents)
    const int b0 = row0 & (BATCH-1);
    const int orow = CHBASE + ((p*NBR)*BATCH + b0 + r15)*NF;
    #pragma unroll
    for (int n = 0; n < 8; n++){
      int c0 = 16*n + 4*g;               // first of 4 consecutive output cols
      int br = c0 >> 5, fc0 = c0 & 31;
      f32x4 v = acc2[n];
      float rsd = xres[n];
      v[0] += rsd; v[1] += rsd; v[2] += rsd; v[3] += rsd;
      *(f32x4*)(out + orow + br*(BATCH*NF) + fc0) = v;
    }
  }
}

extern "C" void kernel_launch(void* const* d_in, const int* in_sizes, int n_in,
                              void* d_out, int out_size, void* d_ws, size_t ws_size,
                              hipStream_t stream){
  const float* x   = (const float*)d_in[0];
  const float* gf  = (const float*)d_in[1];
  const int*   pidx= (const int*)d_in[2];
  const float* W1  = (const float*)d_in[3];
  const float* b1  = (const float*)d_in[4];
  const float* W2  = (const float*)d_in[5];
  const float* b2  = (const float*)d_in[6];
  float* out = (float*)d_out;
  float* G1  = (float*)d_ws;             // 2048*128*4 = 1 MB scratch

  k_g1  <<<(BATCH*DOUT)/256, 256, 0, stream>>>(gf, W1, b1, G1);
  k_main<<<MLPBLK + CPBLK, 256, 0, stream>>>(x, pidx, W1, W2, b2, G1, out);
}

// Round 3
// 162.861 us; speedup vs baseline: 1.2283x; 1.2283x over previous
//
#include <hip/hip_runtime.h>

#define BATCH   2048
#define NPAR    256
#define NF      32
#define NG      16
#define NBR     4
#define OFS     262144
#define DOUT    128
#define NROWSX  (OFS + NPAR*BATCH)     // 786432 rows of x
#define MROWS   (NPAR*BATCH)           // 524288 parent rows
#define NTILES  (MROWS/16)             // 32768 16-row tiles
#define CHBASE  (NROWSX*NF)            // float offset of children region in out
#define NMLP    4096                   // MLP blocks (8 waves x 1 tile each)
#define NCOPY   2048                   // copy blocks

typedef short bf16x8 __attribute__((ext_vector_type(8)));   // 8 bf16 bit-patterns
typedef float f32x4  __attribute__((ext_vector_type(4)));

// ws layout (bytes): [0,1MB) G1 f32 | [1MB,1MB+32KB) W2frag bf16 | +8KB W1frag bf16
#define WSOFF_W2F  1048576
#define WSOFF_W1F  (1048576 + 32768)

__device__ __forceinline__ unsigned short f2bf(float f){
  unsigned int u = __float_as_uint(f);
  u += 0x7FFFu + ((u >> 16) & 1u);          // RNE
  return (unsigned short)(u >> 16);
}

// blocks [0,1024): G1[e][j] = b1[j] + sum_k global[e][k] * W1[32+k][j]
// blocks [1024,1034): pack W2 / W1-feature-half into bf16 MFMA fragments.
__global__ void k_g1(const float* __restrict__ gf, const float* __restrict__ W1,
                     const float* __restrict__ b1, const float* __restrict__ W2,
                     char* __restrict__ ws){
  int bid = blockIdx.x, tid = threadIdx.x;
  if (bid < 1024){
    int idx = bid*256 + tid;
    int e = idx >> 7, j = idx & 127;
    float s = b1[j];
    const float* grow = gf + e*NG;
    const float* w = W1 + NF*DOUT + j;
    #pragma unroll
    for (int k = 0; k < NG; k++) s = fmaf(grow[k], w[k*DOUT], s);
    ((float*)ws)[idx] = s;
    return;
  }
  int t = (bid - 1024)*256 + tid;          // 0..2559
  if (t < 2048){
    // W2 fragment uint4 t: f = t>>6 (kk*8+n), lane l = t&63
    int f = t >> 6, l = t & 63;
    int kk = f >> 3, n = f & 7;
    int krow = 32*kk + 8*(l >> 4);
    int col  = 16*n + (l & 15);
    union { uint4 q; unsigned short u[8]; } w;
    #pragma unroll
    for (int e = 0; e < 8; e++) w.u[e] = f2bf(W2[(krow + e)*DOUT + col]);
    ((uint4*)(ws + WSOFF_W2F))[t] = w.q;
  } else {
    int q = t - 2048;                      // 0..511
    int n = q >> 6, l = q & 63;
    int kb = 8*(l >> 4);
    int col = 16*n + (l & 15);
    union { uint4 v; unsigned short u[8]; } w;
    #pragma unroll
    for (int e = 0; e < 8; e++) w.u[e] = f2bf(W1[(kb + e)*DOUT + col]);
    ((uint4*)(ws + WSOFF_W1F))[q] = w.v;
  }
}

// Merged main kernel, 512 threads. bid%3==2 -> copy path; else MLP path.
// MLP: 8 waves/block, each wave owns one 16-row tile.
__global__ __launch_bounds__(512, 4) void k_main(
    const float* __restrict__ x, const int* __restrict__ pidx,
    const float* __restrict__ b2, const char* __restrict__ ws,
    float* __restrict__ out)
{
  __shared__ uint4 sB2[2048];   // 32 KB: W2 B-fragments [frag(kk*8+n)][lane]
  __shared__ uint4 sW1[512];    //  8 KB: W1 B-fragments [frag n][lane]
  __shared__ uint4 sH1[2048];   // 32 KB: per-wave 4KB h1 tile (bf16, swizzled)

  const int bid = blockIdx.x;
  const int tid = threadIdx.x;

  if (bid % 3 == 2){
    // ---- copy path: out[0:NROWSX*NF] = x, pure bandwidth ----
    const int cid = bid / 3;
    const int n = NROWSX*NF/4;
    const float4* src4 = (const float4*)x;
    float4* dst4 = (float4*)out;
    for (int i = cid*512 + tid; i < n; i += NCOPY*512)
      dst4[i] = src4[i];
    return;
  }
  const int mid = (bid/3)*2 + (bid % 3);   // 0..NMLP-1

  // ---- stage pre-packed fragments into LDS (5 x 16B per thread) ----
  const uint4* W2f = (const uint4*)(ws + WSOFF_W2F);
  const uint4* W1f = (const uint4*)(ws + WSOFF_W1F);
  #pragma unroll
  for (int i = 0; i < 4; i++) sB2[i*512 + tid] = W2f[i*512 + tid];
  sW1[tid] = W1f[tid & 511];
  __syncthreads();

  const int lane = tid & 63;
  const int wv   = tid >> 6;
  const int r15  = lane & 15;
  const int g    = lane >> 4;
  const float* G1 = (const float*)ws;

  char* h1base = (char*)sH1 + wv*4096;
  const bf16x8* B2f = (const bf16x8*)sB2;
  const bf16x8* B1f = (const bf16x8*)sW1;

  const int tl   = mid*8 + wv;             // tile index
  const int row0 = tl*16;

  // This lane's batch row within the tile is r15 (transposed layout).
  const int idxA = pidx[row0 + r15];

  // x row: A-fragment (cols 8g..8g+7) + residual scalars (col 4n+g)
  const float* ap = x + idxA*NF + 8*g;
  float4 a0 = *(const float4*)ap;
  float4 a1 = *(const float4*)(ap + 4);
  float xres[8];
  #pragma unroll
  for (int n = 0; n < 8; n++) xres[n] = x[idxA*NF + 4*n + g];

  union { bf16x8 v; unsigned short u[8]; } af;
  af.u[0]=f2bf(a0.x); af.u[1]=f2bf(a0.y); af.u[2]=f2bf(a0.z); af.u[3]=f2bf(a0.w);
  af.u[4]=f2bf(a1.x); af.u[5]=f2bf(a1.y); af.u[6]=f2bf(a1.z); af.u[7]=f2bf(a1.w);

  // GEMM1 (transposed): acc1[n][r] = h1[r15][16n+4g+r], G1 (bias+global) folded in
  const int g1r = idxA & (BATCH-1);
  f32x4 acc1[8];
  #pragma unroll
  for (int n = 0; n < 8; n++)
    acc1[n] = *(const f32x4*)(G1 + g1r*DOUT + 16*n + 4*g);
  #pragma unroll
  for (int n = 0; n < 8; n++)
    acc1[n] = __builtin_amdgcn_mfma_f32_16x16x32_bf16(B1f[n*64 + lane], af.v, acc1[n], 0, 0, 0);

  // leaky-relu, pack 4 bf16, ds_write_b64 into swizzled [16][128] tile
  #pragma unroll
  for (int n = 0; n < 8; n++){
    float v0 = acc1[n][0], v1 = acc1[n][1], v2 = acc1[n][2], v3 = acc1[n][3];
    v0 = v0 > 0.f ? v0 : 0.01f*v0;
    v1 = v1 > 0.f ? v1 : 0.01f*v1;
    v2 = v2 > 0.f ? v2 : 0.01f*v2;
    v3 = v3 > 0.f ? v3 : 0.01f*v3;
    uint2 pk;
    pk.x = (unsigned)f2bf(v0) | ((unsigned)f2bf(v1) << 16);
    pk.y = (unsigned)f2bf(v2) | ((unsigned)f2bf(v3) << 16);
    int off = r15*256 + (16*n + 4*g)*2;
    off ^= (r15 & 7) << 4;
    *(uint2*)(h1base + off) = pk;
  }
  // wave-private LDS tile: compiler orders via lgkmcnt; no barrier needed.

  // GEMM2 (transposed): acc2[n][r] = proj[r15][16n+4g+r], b2 folded into init
  f32x4 acc2[8];
  #pragma unroll
  for (int n = 0; n < 8; n++)
    acc2[n] = *(const f32x4*)(b2 + 16*n + 4*g);
  #pragma unroll
  for (int kk = 0; kk < 4; kk++){
    int roff = r15*256 + 64*kk + 16*g;
    roff ^= (r15 & 7) << 4;
    bf16x8 a2 = *(const bf16x8*)(h1base + roff);
    #pragma unroll
    for (int n = 0; n < 8; n++)
      acc2[n] = __builtin_amdgcn_mfma_f32_16x16x32_bf16(B2f[(kk*8 + n)*64 + lane], a2, acc2[n], 0, 0, 0);
  }

  // epilogue: + repeat_interleave residual (col>>2 = 4n+g, constant over r),
  // float4 store to children layout
  const int p  = row0 >> 11;               // parent (tiles never cross parents)
  const int b0 = row0 & (BATCH-1);
  const int orow = CHBASE + ((p*NBR)*BATCH + b0 + r15)*NF;
  #pragma unroll
  for (int n = 0; n < 8; n++){
    int c0 = 16*n + 4*g;                   // first of 4 consecutive output cols
    int br = c0 >> 5, fc0 = c0 & 31;
    f32x4 v = acc2[n];
    float rsd = xres[n];
    v[0] += rsd; v[1] += rsd; v[2] += rsd; v[3] += rsd;
    *(f32x4*)(out + orow + br*(BATCH*NF) + fc0) = v;
  }
}

extern "C" void kernel_launch(void* const* d_in, const int* in_sizes, int n_in,
                              void* d_out, int out_size, void* d_ws, size_t ws_size,
                              hipStream_t stream){
  const float* x   = (const float*)d_in[0];
  const float* gf  = (const float*)d_in[1];
  const int*   pidx= (const int*)d_in[2];
  const float* W1  = (const float*)d_in[3];
  const float* b1  = (const float*)d_in[4];
  const float* W2  = (const float*)d_in[5];
  const float* b2  = (const float*)d_in[6];
  float* out = (float*)d_out;
  char* ws   = (char*)d_ws;               // 1MB G1 + 40KB packed fragments

  k_g1  <<<1034, 256, 0, stream>>>(gf, W1, b1, W2, ws);
  k_main<<<NMLP + NCOPY, 512, 0, stream>>>(x, pidx, b2, ws, out);
}